// Round 5
// baseline (360.961 us; speedup 1.0000x reference)
//
#include <hip/hip_runtime.h>
#include <hip/hip_bf16.h>
#include <cstdint>

// ---- problem dims ----
#define L_SEQ   2048
#define DM      1024   // d_model
#define DI      2048   // d_inner
#define DXB     512
#define DS      16     // d_state
#define DTR     64     // dt_rank
#define GH      128    // C-heads = DI/DS
#define DP      5184   // 2*DI + 2*DXB + DTR

// zxbcdt column offsets
#define OFF_Z   0
#define OFF_X   2048
#define OFF_B   2560
#define OFF_C   3072
#define OFF_DT  5120

// scan segmentation: 64 segments x 32 steps -> 512 blocks/scan kernel
#define NSEG    64
#define SEGLEN  32

typedef __bf16 bf16x8 __attribute__((ext_vector_type(8)));
typedef float  f32x4  __attribute__((ext_vector_type(4)));

__device__ __forceinline__ float siluf(float x) {
  return x / (1.f + __expf(-x));
}
__device__ __forceinline__ float softplusf(float x) {
  return x > 20.f ? x : log1pf(__expf(x));
}
__device__ __forceinline__ unsigned short f2bf(float f) {
  union { float f; unsigned u; } v; v.f = f;
  unsigned r = v.u + 0x7fffu + ((v.u >> 16) & 1u);
  return (unsigned short)(r >> 16);
}
// async global->LDS, 16B/lane. LDS dest must be wave-uniform base + lane*16.
__device__ __forceinline__ void gload16(const void* g, void* l) {
  __builtin_amdgcn_global_load_lds((const __attribute__((address_space(1))) void*)g,
                                   (__attribute__((address_space(3))) void*)l, 16, 0, 0);
}

// ---------------------------------------------------------------------------
// bf16 MFMA GEMM (R3-proven 128x128 tile, 256 thr, 4 waves @ 64x64).
// C[M,N](f32) (+)= A[M,K](bf16 row-major) * BT[N,K](bf16)^T
// MODE 0: plain store. MODE 1: atomicAdd (split-K over blockIdx.z).
// Requires M%128==0, K%32==0; N tail via clamp+guard.
// Grid-limited TLP fix: use split-K (blockIdx.z) to raise blocks/CU.
// ---------------------------------------------------------------------------
template<int MODE>
__global__ __launch_bounds__(256) void mfma_gemm(
    const unsigned short* __restrict__ A,
    const unsigned short* __restrict__ BT,
    float* __restrict__ C, int ldc,
    int N, int K, int ktiles)
{
  __shared__ __align__(16) unsigned short Asg[4096];
  __shared__ __align__(16) unsigned short Bsg[4096];

  const int tid  = threadIdx.x;
  const int wave = tid >> 6, lane = tid & 63;
  const int row0 = blockIdx.y * 128;
  const int col0 = blockIdx.x * 128;
  const int kbase = blockIdx.z * ktiles * 32;

  const int s0 = tid, s1 = tid + 256;
  const int rt0 = s0 >> 6, q0 = (s0 >> 4) & 3, m0 = s0 & 15;
  const int rt1 = s1 >> 6, q1 = (s1 >> 4) & 3, m1 = s1 & 15;
  const size_t aoff0 = (size_t)(row0 + rt0 * 16 + m0) * K + q0 * 8 + kbase;
  const size_t aoff1 = (size_t)(row0 + rt1 * 16 + m1) * K + q1 * 8 + kbase;
  int c0i = col0 + rt0 * 16 + m0; if (c0i > N - 1) c0i = N - 1;
  int c1i = col0 + rt1 * 16 + m1; if (c1i > N - 1) c1i = N - 1;
  const size_t boff0 = (size_t)c0i * K + q0 * 8 + kbase;
  const size_t boff1 = (size_t)c1i * K + q1 * 8 + kbase;

  f32x4 acc[4][4];
#pragma unroll
  for (int i = 0; i < 4; ++i)
#pragma unroll
    for (int j = 0; j < 4; ++j) acc[i][j] = (f32x4)0.f;

  const int warow = (wave >> 1) * 4;
  const int wacol = (wave & 1) * 4;

  for (int kt = 0; kt < ktiles; ++kt) {
    const int k0 = kt * 32;
    gload16(A  + aoff0 + k0, Asg + s0 * 8);
    gload16(A  + aoff1 + k0, Asg + s0 * 8 + 2048);
    gload16(BT + boff0 + k0, Bsg + s0 * 8);
    gload16(BT + boff1 + k0, Bsg + s0 * 8 + 2048);
    __syncthreads();

    bf16x8 af[4], bfr[4];
#pragma unroll
    for (int i = 0; i < 4; ++i)
      af[i] = *(const bf16x8*)(Asg + (warow + i) * 512 + lane * 8);
#pragma unroll
    for (int j = 0; j < 4; ++j)
      bfr[j] = *(const bf16x8*)(Bsg + (wacol + j) * 512 + lane * 8);
#pragma unroll
    for (int i = 0; i < 4; ++i)
#pragma unroll
      for (int j = 0; j < 4; ++j)
        acc[i][j] = __builtin_amdgcn_mfma_f32_16x16x32_bf16(af[i], bfr[j], acc[i][j], 0, 0, 0);
    __syncthreads();
  }

  // epilogue: C/D layout col=lane&15, row=(lane>>4)*4+reg
#pragma unroll
  for (int i = 0; i < 4; ++i) {
    const int rbase = row0 + (warow + i) * 16 + ((lane >> 4) << 2);
#pragma unroll
    for (int j = 0; j < 4; ++j) {
      const int col = col0 + (wacol + j) * 16 + (lane & 15);
      if (col < N) {
#pragma unroll
        for (int r = 0; r < 4; ++r) {
          float* p = C + (size_t)(rbase + r) * ldc + col;
          if (MODE == 0) *p = acc[i][j][r];
          else atomicAdd(p, acc[i][j][r]);
        }
      }
    }
  }
}

// ---------------------------------------------------------------------------
// fp32 GEMM for the K=64 delta GEMM. MODE 1: softplus(acc + 2*bias[col]).
// ---------------------------------------------------------------------------
template<int MODE>
__global__ __launch_bounds__(256, 2) void gemm128(
    const float* __restrict__ A, int lda, int aoff,
    const float* __restrict__ B, int ldb,
    float* __restrict__ C, int ldc,
    const float* __restrict__ bias,
    int M, int N, int Kbeg, int Klen)
{
  __shared__ __align__(16) float As[16][132];
  __shared__ __align__(16) float Bs[16][132];

  const int tid = threadIdx.x;
  const int row0 = blockIdx.y * 128;
  const int col0 = blockIdx.x * 128;
  const int kb = Kbeg + blockIdx.z * Klen;

  const int tx = tid & 15, ty = tid >> 4;
  const int ar = tid >> 2, aq = (tid & 3) << 2;
  const int br = tid >> 5, bq = (tid & 31) << 2;

  float acc[8][8];
#pragma unroll
  for (int i = 0; i < 8; ++i)
#pragma unroll
    for (int j = 0; j < 8; ++j) acc[i][j] = 0.f;

  float4 ra0, ra1, rb0, rb1;
  const int ktiles = Klen >> 4;

  auto loadG = [&](int kt) {
    const int k0 = kb + (kt << 4);
    const float* Ap = A + (size_t)(row0 + ar) * lda + aoff + k0 + aq;
    ra0 = *(const float4*)Ap;
    ra1 = *(const float4*)(Ap + (size_t)64 * lda);
    const int cb_ = col0 + bq;
    if (cb_ < N) {
      const float* Bp = B + (size_t)(k0 + br) * ldb + cb_;
      rb0 = *(const float4*)Bp;
      rb1 = *(const float4*)(Bp + (size_t)8 * ldb);
    } else {
      rb0 = make_float4(0.f, 0.f, 0.f, 0.f);
      rb1 = make_float4(0.f, 0.f, 0.f, 0.f);
    }
  };

  loadG(0);
  for (int kt = 0; kt < ktiles; ++kt) {
    __syncthreads();
    As[aq + 0][ar] = ra0.x; As[aq + 1][ar] = ra0.y;
    As[aq + 2][ar] = ra0.z; As[aq + 3][ar] = ra0.w;
    As[aq + 0][ar + 64] = ra1.x; As[aq + 1][ar + 64] = ra1.y;
    As[aq + 2][ar + 64] = ra1.z; As[aq + 3][ar + 64] = ra1.w;
    *(float4*)&Bs[br][bq] = rb0;
    *(float4*)&Bs[br + 8][bq] = rb1;
    __syncthreads();
    if (kt + 1 < ktiles) loadG(kt + 1);

#pragma unroll
    for (int k = 0; k < 16; ++k) {
      float4 a0 = *(const float4*)&As[k][ty * 4];
      float4 a1 = *(const float4*)&As[k][ty * 4 + 64];
      float4 b0 = *(const float4*)&Bs[k][tx * 4];
      float4 b1 = *(const float4*)&Bs[k][tx * 4 + 64];
      float av[8] = {a0.x, a0.y, a0.z, a0.w, a1.x, a1.y, a1.z, a1.w};
      float bv[8] = {b0.x, b0.y, b0.z, b0.w, b1.x, b1.y, b1.z, b1.w};
#pragma unroll
      for (int i = 0; i < 8; ++i)
#pragma unroll
        for (int j = 0; j < 8; ++j)
          acc[i][j] = fmaf(av[i], bv[j], acc[i][j]);
    }
  }

#pragma unroll
  for (int half = 0; half < 2; ++half) {
#pragma unroll
    for (int i = 0; i < 4; ++i) {
      const int rr = row0 + half * 64 + ty * 4 + i;
      if (rr >= M) continue;
      const int ii = half * 4 + i;
#pragma unroll
      for (int jh = 0; jh < 2; ++jh) {
        const int cc = col0 + jh * 64 + tx * 4;
        if (cc >= N) continue;
        const int jj = jh * 4;
        float* Cp = C + (size_t)rr * ldc + cc;
        if (MODE == 1) {
          float4 bi = *(const float4*)&bias[cc];
          float4 v;
          v.x = softplusf(acc[ii][jj + 0] + 2.f * bi.x);
          v.y = softplusf(acc[ii][jj + 1] + 2.f * bi.y);
          v.z = softplusf(acc[ii][jj + 2] + 2.f * bi.z);
          v.w = softplusf(acc[ii][jj + 3] + 2.f * bi.w);
          *(float4*)Cp = v;
        } else {
          float4 v = make_float4(acc[ii][jj], acc[ii][jj + 1], acc[ii][jj + 2], acc[ii][jj + 3]);
          *(float4*)Cp = v;
        }
      }
    }
  }
}

// ---------------------------------------------------------------------------
__global__ __launch_bounds__(256) void cast_bf16_k(
    const float* __restrict__ in, unsigned short* __restrict__ out, int n4)
{
  const int t = blockIdx.x * 256 + threadIdx.x;
  if (t < n4) {
    float4 v = ((const float4*)in)[t];
    ushort4 o;
    o.x = f2bf(v.x); o.y = f2bf(v.y); o.z = f2bf(v.z); o.w = f2bf(v.w);
    ((ushort4*)out)[t] = o;
  }
}

// W (R x C fp32) -> WT (C x R bf16)
__global__ __launch_bounds__(256) void transpose_cast_k(
    const float* __restrict__ W, unsigned short* __restrict__ WT, int R, int C)
{
  __shared__ float t[32][33];
  const int c0 = blockIdx.x * 32, r0 = blockIdx.y * 32;
  const int x = threadIdx.x & 31, y = threadIdx.x >> 5;
#pragma unroll
  for (int i = 0; i < 4; ++i)
    t[y * 4 + i][x] = W[(size_t)(r0 + y * 4 + i) * C + c0 + x];
  __syncthreads();
#pragma unroll
  for (int i = 0; i < 4; ++i)
    WT[(size_t)(c0 + y * 4 + i) * R + r0 + x] = f2bf(t[x][y * 4 + i]);
}

// ---------------------------------------------------------------------------
__global__ __launch_bounds__(256) void conv_silu_k(
    const float* __restrict__ zx, const float* __restrict__ cw,
    const float* __restrict__ cb, float* __restrict__ xc)
{
  const int t = blockIdx.x * 256 + threadIdx.x;
  const int c = t & (DXB - 1);
  const int l = t >> 9;
  const float* col = zx + OFF_X + c;
  const float w0 = cw[c * 4 + 0], w1 = cw[c * 4 + 1];
  const float w2 = cw[c * 4 + 2], w3 = cw[c * 4 + 3];
  float acc = cb[c] + w3 * col[(size_t)l * DP];
  if (l >= 1) acc = fmaf(w2, col[(size_t)(l - 1) * DP], acc);
  if (l >= 2) acc = fmaf(w1, col[(size_t)(l - 2) * DP], acc);
  if (l >= 3) acc = fmaf(w0, col[(size_t)(l - 3) * DP], acc);
  xc[t] = siluf(acc);
}

// ---------------------------------------------------------------------------
// Scan pass 1: thread owns (g,p) with 16 n-states in registers.
// ---------------------------------------------------------------------------
__global__ __launch_bounds__(256) void scan_p1(
    const float* __restrict__ zx, const float* __restrict__ delta,
    const float* __restrict__ xcv, const float* __restrict__ A_log,
    float* __restrict__ Sout, float* __restrict__ Hout)
{
  const int gb = blockIdx.x, s = blockIdx.y;
  const int tid = threadIdx.x;
  const int lg = tid >> 4, p = tid & 15;
  const int l0 = s * SEGLEN;

  __shared__ __align__(16) float sB[SEGLEN][64];
  __shared__ __align__(16) float sx[SEGLEN][64];

#pragma unroll
  for (int rep = 0; rep < 2; ++rep) {
    const int idx = rep * 256 + tid;
    const int i = idx >> 4, j4 = (idx & 15) << 2;
    gload16(&zx[(size_t)(l0 + i) * DP + OFF_B + gb * 64 + j4], &sB[0][0] + idx * 4);
    gload16(&xcv[(size_t)(l0 + i) * DXB + gb * 64 + j4], &sx[0][0] + idx * 4);
  }

  float An[16];
  {
    const float* ap = A_log + (size_t)gb * 4096 + tid * 16;
#pragma unroll
    for (int n = 0; n < 16; ++n) An[n] = -__expf(ap[n]);
  }
  __syncthreads();

  float h[16];
#pragma unroll
  for (int n = 0; n < 16; ++n) h[n] = 0.f;
  float S = 0.f;

  const float* dtp = delta + (size_t)l0 * DI + gb * 256 + tid;
  const int xj = ((lg >> 2) << 4) + p;
  const int bj = (lg >> 2) << 4;

  float dtc = dtp[0];
  for (int i = 0; i < SEGLEN; ++i) {
    const float dt = dtc;
    if (i + 1 < SEGLEN) dtc = dtp[(size_t)(i + 1) * DI];
    const float dtx = dt * sx[i][xj];
    S += dt;
#pragma unroll
    for (int nq = 0; nq < 4; ++nq) {
      const float4 b4 = *(const float4*)&sB[i][bj + nq * 4];
      const float bb[4] = {b4.x, b4.y, b4.z, b4.w};
#pragma unroll
      for (int k = 0; k < 4; ++k) {
        const int n = nq * 4 + k;
        const float a = __expf(dt * An[n]);
        h[n] = fmaf(a, h[n], dtx * bb[k]);
      }
    }
  }

  Sout[(size_t)s * 2048 + gb * 256 + tid] = S;
  float* hp = Hout + (size_t)s * 32768 + (size_t)gb * 4096 + tid * 16;
#pragma unroll
  for (int nq = 0; nq < 4; ++nq)
    *(float4*)(hp + nq * 4) = make_float4(h[nq * 4], h[nq * 4 + 1], h[nq * 4 + 2], h[nq * 4 + 3]);
}

// ---------------------------------------------------------------------------
// Carry kernel: exclusive scan over segments per flat state e=(g,p,n).
// ---------------------------------------------------------------------------
__global__ __launch_bounds__(256) void scan_carry(
    const float* __restrict__ A_log, const float* __restrict__ Sin,
    const float* __restrict__ Hin, float* __restrict__ Hcarry)
{
  const int e = blockIdx.x * 256 + threadIdx.x;
  const float An = -__expf(A_log[e]);
  const int gp = e >> 4;
  float h = 0.f;
  for (int s = 0; s < NSEG; ++s) {
    Hcarry[(size_t)s * 32768 + e] = h;
    const float P = __expf(An * Sin[(size_t)s * 2048 + gp]);
    h = fmaf(P, h, Hin[(size_t)s * 32768 + e]);
  }
}

// ---------------------------------------------------------------------------
// Scan pass 2: load carry, rerun segment, fused y/D/gate epilogue -> bf16 y.
// ---------------------------------------------------------------------------
__global__ __launch_bounds__(256) void scan_p2(
    const float* __restrict__ zx, const float* __restrict__ delta,
    const float* __restrict__ xcv, const float* __restrict__ A_log,
    const float* __restrict__ Dv, const float* __restrict__ Hcarry,
    unsigned short* __restrict__ ybuf)
{
  const int gb = blockIdx.x, s = blockIdx.y;
  const int tid = threadIdx.x;
  const int lg = tid >> 4, p = tid & 15;
  const int l0 = s * SEGLEN;

  __shared__ __align__(16) float sC[SEGLEN][256];
  __shared__ __align__(16) float sB[SEGLEN][64];
  __shared__ __align__(16) float sx[SEGLEN][64];

#pragma unroll
  for (int rep = 0; rep < 8; ++rep) {
    const int idx = rep * 256 + tid;
    const int i = idx >> 6, j4 = (idx & 63) << 2;
    gload16(&zx[(size_t)(l0 + i) * DP + OFF_C + gb * 256 + j4], &sC[0][0] + idx * 4);
  }
#pragma unroll
  for (int rep = 0; rep < 2; ++rep) {
    const int idx = rep * 256 + tid;
    const int i = idx >> 4, j4 = (idx & 15) << 2;
    gload16(&zx[(size_t)(l0 + i) * DP + OFF_B + gb * 64 + j4], &sB[0][0] + idx * 4);
    gload16(&xcv[(size_t)(l0 + i) * DXB + gb * 64 + j4], &sx[0][0] + idx * 4);
  }

  float An[16], h[16];
  {
    const float* ap = A_log + (size_t)gb * 4096 + tid * 16;
#pragma unroll
    for (int n = 0; n < 16; ++n) An[n] = -__expf(ap[n]);
    const float* hp = Hcarry + (size_t)s * 32768 + (size_t)gb * 4096 + tid * 16;
#pragma unroll
    for (int nq = 0; nq < 4; ++nq) {
      const float4 h4 = *(const float4*)(hp + nq * 4);
      h[nq * 4] = h4.x; h[nq * 4 + 1] = h4.y; h[nq * 4 + 2] = h4.z; h[nq * 4 + 3] = h4.w;
    }
  }
  const float Dd = Dv[gb * 256 + tid];
  __syncthreads();

  const float* dtp = delta + (size_t)l0 * DI + gb * 256 + tid;
  const float* zp  = zx + (size_t)l0 * DP + OFF_Z + gb * 256 + tid;
  unsigned short* yp = ybuf + (size_t)l0 * DI + gb * 256 + tid;
  const int xj = ((lg >> 2) << 4) + p;
  const int bj = (lg >> 2) << 4;
  const int cj = lg << 4;

  float dtc = dtp[0], zc = zp[0];
  for (int i = 0; i < SEGLEN; ++i) {
    const float dt = dtc, zv = zc;
    if (i + 1 < SEGLEN) {
      dtc = dtp[(size_t)(i + 1) * DI];
      zc  = zp[(size_t)(i + 1) * DP];
    }
    const float xv = sx[i][xj];
    const float dtx = dt * xv;
    float y = 0.f;
#pragma unroll
    for (int nq = 0; nq < 4; ++nq) {
      const float4 b4 = *(const float4*)&sB[i][bj + nq * 4];
      const float4 c4 = *(const float4*)&sC[i][cj + nq * 4];
      const float bb[4] = {b4.x, b4.y, b4.z, b4.w};
      const float cc[4] = {c4.x, c4.y, c4.z, c4.w};
#pragma unroll
      for (int k = 0; k < 4; ++k) {
        const int n = nq * 4 + k;
        const float a = __expf(dt * An[n]);
        h[n] = fmaf(a, h[n], dtx * bb[k]);
        y = fmaf(h[n], cc[k], y);
      }
    }
    yp[(size_t)i * DI] = f2bf((y + Dd * xv) * siluf(zv));
  }
}

__global__ __launch_bounds__(256) void zero_f32(float* __restrict__ p, int n4)
{
  const int t = blockIdx.x * 256 + threadIdx.x;
  if (t < n4) ((float4*)p)[t] = make_float4(0.f, 0.f, 0.f, 0.f);
}

// ---------------------------------------------------------------------------
extern "C" void kernel_launch(void* const* d_in, const int* in_sizes, int n_in,
                              void* d_out, int out_size, void* d_ws, size_t ws_size,
                              hipStream_t stream)
{
  const float* hidden  = (const float*)d_in[0];
  const float* W_in    = (const float*)d_in[1];
  const float* conv_w  = (const float*)d_in[2];
  const float* conv_b  = (const float*)d_in[3];
  const float* W_dt    = (const float*)d_in[4];
  const float* dt_bias = (const float*)d_in[5];
  const float* A_log   = (const float*)d_in[6];
  const float* Dvec    = (const float*)d_in[7];
  const float* W_out   = (const float*)d_in[8];
  float* out = (float*)d_out;

  // --- workspace layout (lifetime-aliased; max footprint 80,740,352 B) ---
  float* ws = (float*)d_ws;
  float* zx     = ws;                       // [0, 10,616,832) f32 — alive all
  float* delta  = ws + 10616832;            // [10,616,832, 14,811,136) f32
  float* xcv    = ws + 14811136;            // [14,811,136, 15,859,712) f32
  float* Sbuf   = ws + 15859712;            // 131,072 f32
  float* Hbuf   = ws + 15990784;            // 2,097,152 f32 (ends 18,087,936)
  float* Hcarry = ws + 18087936;            // 2,097,152 f32 (ends 20,185,088)
  // phase-A aliases (dead before delta/xcv written):
  unsigned short* Abf  = (unsigned short*)(ws + 10616832);  // 2,097,152 u16
  unsigned short* WinT = (unsigned short*)(ws + 11665408);  // 5,308,416 u16
  // phase-D/E aliases:
  unsigned short* Ybf   = (unsigned short*)(ws + 15859712); // 4,194,304 u16 over S+H
  unsigned short* WoutT = (unsigned short*)(ws + 10616832); // 2,097,152 u16 over delta

  // 1. cast hidden -> bf16; transpose+cast W_in; zero zx for split-K atomics
  cast_bf16_k<<<dim3((L_SEQ * DM / 4) / 256), 256, 0, stream>>>(hidden, Abf, L_SEQ * DM / 4);
  transpose_cast_k<<<dim3(DP / 32, DM / 32), 256, 0, stream>>>(W_in, WinT, DM, DP);
  zero_f32<<<dim3((L_SEQ * DP / 4 + 255) / 256), 256, 0, stream>>>(zx, L_SEQ * DP / 4);

  // 2. in-projection (bf16 MFMA, split-K=2 atomic): zx = hidden @ W_in
  mfma_gemm<1><<<dim3(41, 16, 2), 256, 0, stream>>>(Abf, WinT, zx, DP, DP, DM, DM / 2 / 32);

  // 3. causal depthwise conv + silu
  conv_silu_k<<<dim3((L_SEQ * DXB) / 256), 256, 0, stream>>>(zx, conv_w, conv_b, xcv);

  // 4. delta = softplus(dtr @ W_dt + 2*dt_bias)  (fp32, K=64)
  gemm128<1><<<dim3(16, 16), 256, 0, stream>>>(
      zx, DP, OFF_DT, W_dt, DI, delta, DI, dt_bias, L_SEQ, DI, 0, DTR);

  // 5. scan pass 1: per-segment (S, H)
  scan_p1<<<dim3(8, NSEG), 256, 0, stream>>>(zx, delta, xcv, A_log, Sbuf, Hbuf);

  // 6. exclusive segment-carry scan
  scan_carry<<<dim3(128), 256, 0, stream>>>(A_log, Sbuf, Hbuf, Hcarry);

  // 7. scan pass 2 -> y (bf16) with fused D*x + silu(z) gate
  scan_p2<<<dim3(8, NSEG), 256, 0, stream>>>(zx, delta, xcv, A_log, Dvec, Hcarry, Ybf);

  // 8. transpose+cast W_out (into delta region, dead after scan_p2)
  transpose_cast_k<<<dim3(DM / 32, DI / 32), 256, 0, stream>>>(W_out, WoutT, DI, DM);

  // 9. out-projection (bf16 MFMA, split-K=8 atomic)
  zero_f32<<<dim3(out_size / 4 / 256), 256, 0, stream>>>(out, out_size / 4);
  mfma_gemm<1><<<dim3(8, 16, 8), 256, 0, stream>>>(Ybf, WoutT, out, DM, DM, DI, DI / 8 / 32);
}

// Round 6
// 282.753 us; speedup vs baseline: 1.2766x; 1.2766x over previous
//
#include <hip/hip_runtime.h>
#include <hip/hip_bf16.h>
#include <cstdint>

// ---- problem dims ----
#define L_SEQ   2048
#define DM      1024   // d_model
#define DI      2048   // d_inner
#define DXB     512
#define DS      16     // d_state
#define DTR     64     // dt_rank
#define GH      128    // C-heads = DI/DS
#define DP      5184   // 2*DI + 2*DXB + DTR

// zxbcdt column offsets
#define OFF_Z   0
#define OFF_X   2048
#define OFF_B   2560
#define OFF_C   3072
#define OFF_DT  5120

// scan segmentation: 64 segments x 32 steps -> 512 blocks/scan kernel
#define NSEG    64
#define SEGLEN  32

typedef __bf16 bf16x8 __attribute__((ext_vector_type(8)));
typedef float  f32x4  __attribute__((ext_vector_type(4)));

__device__ __forceinline__ float siluf(float x) {
  return x / (1.f + __expf(-x));
}
__device__ __forceinline__ float softplusf(float x) {
  return x > 20.f ? x : log1pf(__expf(x));
}
__device__ __forceinline__ unsigned short f2bf(float f) {
  union { float f; unsigned u; } v; v.f = f;
  unsigned r = v.u + 0x7fffu + ((v.u >> 16) & 1u);
  return (unsigned short)(r >> 16);
}
// async global->LDS, 16B/lane. LDS dest must be wave-uniform base + lane*16.
__device__ __forceinline__ void gload16(const void* g, void* l) {
  __builtin_amdgcn_global_load_lds((const __attribute__((address_space(1))) void*)g,
                                   (__attribute__((address_space(3))) void*)l, 16, 0, 0);
}

// ---------------------------------------------------------------------------
// bf16 MFMA GEMM, 128x128 tile, 256 thr, 4 waves @ 64x64, DOUBLE-BUFFERED LDS.
// C[M,N](f32) (+)= A[M,K](bf16 row-major) * BT[N,K](bf16)^T
// One barrier per k-iter; prefetch for kt+1 issued AFTER the barrier so the
// vmcnt(0) drain at the NEXT barrier pays only the residual latency (loads
// overlap a full compute phase). Race-free: threads pass the barrier only
// after their ds_reads completed (lgkmcnt-waited before MFMA consumption).
// MODE 0: plain store. MODE 1: atomicAdd (split-K over blockIdx.z; only for
// SMALL outputs — split-K atomics on large C regressed 2x in R5).
// ---------------------------------------------------------------------------
template<int MODE>
__global__ __launch_bounds__(256) void mfma_gemm(
    const unsigned short* __restrict__ A,
    const unsigned short* __restrict__ BT,
    float* __restrict__ C, int ldc,
    int N, int K, int ktiles)
{
  __shared__ __align__(16) unsigned short Asg[2][4096];
  __shared__ __align__(16) unsigned short Bsg[2][4096];

  const int tid  = threadIdx.x;
  const int wave = tid >> 6, lane = tid & 63;
  const int row0 = blockIdx.y * 128;
  const int col0 = blockIdx.x * 128;
  const int kbase = blockIdx.z * ktiles * 32;

  const int s0 = tid, s1 = tid + 256;
  const int rt0 = s0 >> 6, q0 = (s0 >> 4) & 3, m0 = s0 & 15;
  const int rt1 = s1 >> 6, q1 = (s1 >> 4) & 3, m1 = s1 & 15;
  const size_t aoff0 = (size_t)(row0 + rt0 * 16 + m0) * K + q0 * 8 + kbase;
  const size_t aoff1 = (size_t)(row0 + rt1 * 16 + m1) * K + q1 * 8 + kbase;
  int c0i = col0 + rt0 * 16 + m0; if (c0i > N - 1) c0i = N - 1;
  int c1i = col0 + rt1 * 16 + m1; if (c1i > N - 1) c1i = N - 1;
  const size_t boff0 = (size_t)c0i * K + q0 * 8 + kbase;
  const size_t boff1 = (size_t)c1i * K + q1 * 8 + kbase;

  f32x4 acc[4][4];
#pragma unroll
  for (int i = 0; i < 4; ++i)
#pragma unroll
    for (int j = 0; j < 4; ++j) acc[i][j] = (f32x4)0.f;

  const int warow = (wave >> 1) * 4;
  const int wacol = (wave & 1) * 4;

  // prologue: stage tile 0 into buffer 0
  gload16(A  + aoff0, Asg[0] + s0 * 8);
  gload16(A  + aoff1, Asg[0] + s0 * 8 + 2048);
  gload16(BT + boff0, Bsg[0] + s0 * 8);
  gload16(BT + boff1, Bsg[0] + s0 * 8 + 2048);

  for (int kt = 0; kt < ktiles; ++kt) {
    const int cur = kt & 1;
    __syncthreads();  // drains prev-iter loads (publishes buf[cur]); all reads of buf[1-cur] done
    if (kt + 1 < ktiles) {
      const int k0 = (kt + 1) * 32;
      gload16(A  + aoff0 + k0, Asg[1 - cur] + s0 * 8);
      gload16(A  + aoff1 + k0, Asg[1 - cur] + s0 * 8 + 2048);
      gload16(BT + boff0 + k0, Bsg[1 - cur] + s0 * 8);
      gload16(BT + boff1 + k0, Bsg[1 - cur] + s0 * 8 + 2048);
    }

    bf16x8 af[4], bfr[4];
#pragma unroll
    for (int i = 0; i < 4; ++i)
      af[i] = *(const bf16x8*)(Asg[cur] + (warow + i) * 512 + lane * 8);
#pragma unroll
    for (int j = 0; j < 4; ++j)
      bfr[j] = *(const bf16x8*)(Bsg[cur] + (wacol + j) * 512 + lane * 8);
#pragma unroll
    for (int i = 0; i < 4; ++i)
#pragma unroll
      for (int j = 0; j < 4; ++j)
        acc[i][j] = __builtin_amdgcn_mfma_f32_16x16x32_bf16(af[i], bfr[j], acc[i][j], 0, 0, 0);
  }

  // epilogue: C/D layout col=lane&15, row=(lane>>4)*4+reg
#pragma unroll
  for (int i = 0; i < 4; ++i) {
    const int rbase = row0 + (warow + i) * 16 + ((lane >> 4) << 2);
#pragma unroll
    for (int j = 0; j < 4; ++j) {
      const int col = col0 + (wacol + j) * 16 + (lane & 15);
      if (col < N) {
#pragma unroll
        for (int r = 0; r < 4; ++r) {
          float* p = C + (size_t)(rbase + r) * ldc + col;
          if (MODE == 0) *p = acc[i][j][r];
          else atomicAdd(p, acc[i][j][r]);
        }
      }
    }
  }
}

// ---------------------------------------------------------------------------
// fp32 GEMM for the K=64 delta GEMM. MODE 1: softplus(acc + 2*bias[col]).
// ---------------------------------------------------------------------------
template<int MODE>
__global__ __launch_bounds__(256, 2) void gemm128(
    const float* __restrict__ A, int lda, int aoff,
    const float* __restrict__ B, int ldb,
    float* __restrict__ C, int ldc,
    const float* __restrict__ bias,
    int M, int N, int Kbeg, int Klen)
{
  __shared__ __align__(16) float As[16][132];
  __shared__ __align__(16) float Bs[16][132];

  const int tid = threadIdx.x;
  const int row0 = blockIdx.y * 128;
  const int col0 = blockIdx.x * 128;
  const int kb = Kbeg + blockIdx.z * Klen;

  const int tx = tid & 15, ty = tid >> 4;
  const int ar = tid >> 2, aq = (tid & 3) << 2;
  const int br = tid >> 5, bq = (tid & 31) << 2;

  float acc[8][8];
#pragma unroll
  for (int i = 0; i < 8; ++i)
#pragma unroll
    for (int j = 0; j < 8; ++j) acc[i][j] = 0.f;

  float4 ra0, ra1, rb0, rb1;
  const int ktiles = Klen >> 4;

  auto loadG = [&](int kt) {
    const int k0 = kb + (kt << 4);
    const float* Ap = A + (size_t)(row0 + ar) * lda + aoff + k0 + aq;
    ra0 = *(const float4*)Ap;
    ra1 = *(const float4*)(Ap + (size_t)64 * lda);
    const int cb_ = col0 + bq;
    if (cb_ < N) {
      const float* Bp = B + (size_t)(k0 + br) * ldb + cb_;
      rb0 = *(const float4*)Bp;
      rb1 = *(const float4*)(Bp + (size_t)8 * ldb);
    } else {
      rb0 = make_float4(0.f, 0.f, 0.f, 0.f);
      rb1 = make_float4(0.f, 0.f, 0.f, 0.f);
    }
  };

  loadG(0);
  for (int kt = 0; kt < ktiles; ++kt) {
    __syncthreads();
    As[aq + 0][ar] = ra0.x; As[aq + 1][ar] = ra0.y;
    As[aq + 2][ar] = ra0.z; As[aq + 3][ar] = ra0.w;
    As[aq + 0][ar + 64] = ra1.x; As[aq + 1][ar + 64] = ra1.y;
    As[aq + 2][ar + 64] = ra1.z; As[aq + 3][ar + 64] = ra1.w;
    *(float4*)&Bs[br][bq] = rb0;
    *(float4*)&Bs[br + 8][bq] = rb1;
    __syncthreads();
    if (kt + 1 < ktiles) loadG(kt + 1);

#pragma unroll
    for (int k = 0; k < 16; ++k) {
      float4 a0 = *(const float4*)&As[k][ty * 4];
      float4 a1 = *(const float4*)&As[k][ty * 4 + 64];
      float4 b0 = *(const float4*)&Bs[k][tx * 4];
      float4 b1 = *(const float4*)&Bs[k][tx * 4 + 64];
      float av[8] = {a0.x, a0.y, a0.z, a0.w, a1.x, a1.y, a1.z, a1.w};
      float bv[8] = {b0.x, b0.y, b0.z, b0.w, b1.x, b1.y, b1.z, b1.w};
#pragma unroll
      for (int i = 0; i < 8; ++i)
#pragma unroll
        for (int j = 0; j < 8; ++j)
          acc[i][j] = fmaf(av[i], bv[j], acc[i][j]);
    }
  }

#pragma unroll
  for (int half = 0; half < 2; ++half) {
#pragma unroll
    for (int i = 0; i < 4; ++i) {
      const int rr = row0 + half * 64 + ty * 4 + i;
      if (rr >= M) continue;
      const int ii = half * 4 + i;
#pragma unroll
      for (int jh = 0; jh < 2; ++jh) {
        const int cc = col0 + jh * 64 + tx * 4;
        if (cc >= N) continue;
        const int jj = jh * 4;
        float* Cp = C + (size_t)rr * ldc + cc;
        if (MODE == 1) {
          float4 bi = *(const float4*)&bias[cc];
          float4 v;
          v.x = softplusf(acc[ii][jj + 0] + 2.f * bi.x);
          v.y = softplusf(acc[ii][jj + 1] + 2.f * bi.y);
          v.z = softplusf(acc[ii][jj + 2] + 2.f * bi.z);
          v.w = softplusf(acc[ii][jj + 3] + 2.f * bi.w);
          *(float4*)Cp = v;
        } else {
          float4 v = make_float4(acc[ii][jj], acc[ii][jj + 1], acc[ii][jj + 2], acc[ii][jj + 3]);
          *(float4*)Cp = v;
        }
      }
    }
  }
}

// ---------------------------------------------------------------------------
__global__ __launch_bounds__(256) void cast_bf16_k(
    const float* __restrict__ in, unsigned short* __restrict__ out, int n4)
{
  const int t = blockIdx.x * 256 + threadIdx.x;
  if (t < n4) {
    float4 v = ((const float4*)in)[t];
    ushort4 o;
    o.x = f2bf(v.x); o.y = f2bf(v.y); o.z = f2bf(v.z); o.w = f2bf(v.w);
    ((ushort4*)out)[t] = o;
  }
}

// W (R x C fp32) -> WT (C x R bf16)
__global__ __launch_bounds__(256) void transpose_cast_k(
    const float* __restrict__ W, unsigned short* __restrict__ WT, int R, int C)
{
  __shared__ float t[32][33];
  const int c0 = blockIdx.x * 32, r0 = blockIdx.y * 32;
  const int x = threadIdx.x & 31, y = threadIdx.x >> 5;
#pragma unroll
  for (int i = 0; i < 4; ++i)
    t[y * 4 + i][x] = W[(size_t)(r0 + y * 4 + i) * C + c0 + x];
  __syncthreads();
#pragma unroll
  for (int i = 0; i < 4; ++i)
    WT[(size_t)(c0 + y * 4 + i) * R + r0 + x] = f2bf(t[x][y * 4 + i]);
}

// ---------------------------------------------------------------------------
__global__ __launch_bounds__(256) void conv_silu_k(
    const float* __restrict__ zx, const float* __restrict__ cw,
    const float* __restrict__ cb, float* __restrict__ xc)
{
  const int t = blockIdx.x * 256 + threadIdx.x;
  const int c = t & (DXB - 1);
  const int l = t >> 9;
  const float* col = zx + OFF_X + c;
  const float w0 = cw[c * 4 + 0], w1 = cw[c * 4 + 1];
  const float w2 = cw[c * 4 + 2], w3 = cw[c * 4 + 3];
  float acc = cb[c] + w3 * col[(size_t)l * DP];
  if (l >= 1) acc = fmaf(w2, col[(size_t)(l - 1) * DP], acc);
  if (l >= 2) acc = fmaf(w1, col[(size_t)(l - 2) * DP], acc);
  if (l >= 3) acc = fmaf(w0, col[(size_t)(l - 3) * DP], acc);
  xc[t] = siluf(acc);
}

// ---------------------------------------------------------------------------
// Scan pass 1: thread owns (g,p) with 16 n-states in registers.
// ---------------------------------------------------------------------------
__global__ __launch_bounds__(256) void scan_p1(
    const float* __restrict__ zx, const float* __restrict__ delta,
    const float* __restrict__ xcv, const float* __restrict__ A_log,
    float* __restrict__ Sout, float* __restrict__ Hout)
{
  const int gb = blockIdx.x, s = blockIdx.y;
  const int tid = threadIdx.x;
  const int lg = tid >> 4, p = tid & 15;
  const int l0 = s * SEGLEN;

  __shared__ __align__(16) float sB[SEGLEN][64];
  __shared__ __align__(16) float sx[SEGLEN][64];

#pragma unroll
  for (int rep = 0; rep < 2; ++rep) {
    const int idx = rep * 256 + tid;
    const int i = idx >> 4, j4 = (idx & 15) << 2;
    gload16(&zx[(size_t)(l0 + i) * DP + OFF_B + gb * 64 + j4], &sB[0][0] + idx * 4);
    gload16(&xcv[(size_t)(l0 + i) * DXB + gb * 64 + j4], &sx[0][0] + idx * 4);
  }

  float An[16];
  {
    const float* ap = A_log + (size_t)gb * 4096 + tid * 16;
#pragma unroll
    for (int n = 0; n < 16; ++n) An[n] = -__expf(ap[n]);
  }
  __syncthreads();

  float h[16];
#pragma unroll
  for (int n = 0; n < 16; ++n) h[n] = 0.f;
  float S = 0.f;

  const float* dtp = delta + (size_t)l0 * DI + gb * 256 + tid;
  const int xj = ((lg >> 2) << 4) + p;
  const int bj = (lg >> 2) << 4;

  float dtc = dtp[0];
  for (int i = 0; i < SEGLEN; ++i) {
    const float dt = dtc;
    if (i + 1 < SEGLEN) dtc = dtp[(size_t)(i + 1) * DI];
    const float dtx = dt * sx[i][xj];
    S += dt;
#pragma unroll
    for (int nq = 0; nq < 4; ++nq) {
      const float4 b4 = *(const float4*)&sB[i][bj + nq * 4];
      const float bb[4] = {b4.x, b4.y, b4.z, b4.w};
#pragma unroll
      for (int k = 0; k < 4; ++k) {
        const int n = nq * 4 + k;
        const float a = __expf(dt * An[n]);
        h[n] = fmaf(a, h[n], dtx * bb[k]);
      }
    }
  }

  Sout[(size_t)s * 2048 + gb * 256 + tid] = S;
  float* hp = Hout + (size_t)s * 32768 + (size_t)gb * 4096 + tid * 16;
#pragma unroll
  for (int nq = 0; nq < 4; ++nq)
    *(float4*)(hp + nq * 4) = make_float4(h[nq * 4], h[nq * 4 + 1], h[nq * 4 + 2], h[nq * 4 + 3]);
}

// ---------------------------------------------------------------------------
// Carry kernel: exclusive scan over segments per flat state e=(g,p,n).
// ---------------------------------------------------------------------------
__global__ __launch_bounds__(256) void scan_carry(
    const float* __restrict__ A_log, const float* __restrict__ Sin,
    const float* __restrict__ Hin, float* __restrict__ Hcarry)
{
  const int e = blockIdx.x * 256 + threadIdx.x;
  const float An = -__expf(A_log[e]);
  const int gp = e >> 4;
  float h = 0.f;
  for (int s = 0; s < NSEG; ++s) {
    Hcarry[(size_t)s * 32768 + e] = h;
    const float P = __expf(An * Sin[(size_t)s * 2048 + gp]);
    h = fmaf(P, h, Hin[(size_t)s * 32768 + e]);
  }
}

// ---------------------------------------------------------------------------
// Scan pass 2: load carry, rerun segment, fused y/D/gate epilogue -> bf16 y.
// ---------------------------------------------------------------------------
__global__ __launch_bounds__(256) void scan_p2(
    const float* __restrict__ zx, const float* __restrict__ delta,
    const float* __restrict__ xcv, const float* __restrict__ A_log,
    const float* __restrict__ Dv, const float* __restrict__ Hcarry,
    unsigned short* __restrict__ ybuf)
{
  const int gb = blockIdx.x, s = blockIdx.y;
  const int tid = threadIdx.x;
  const int lg = tid >> 4, p = tid & 15;
  const int l0 = s * SEGLEN;

  __shared__ __align__(16) float sC[SEGLEN][256];
  __shared__ __align__(16) float sB[SEGLEN][64];
  __shared__ __align__(16) float sx[SEGLEN][64];

#pragma unroll
  for (int rep = 0; rep < 8; ++rep) {
    const int idx = rep * 256 + tid;
    const int i = idx >> 6, j4 = (idx & 63) << 2;
    gload16(&zx[(size_t)(l0 + i) * DP + OFF_C + gb * 256 + j4], &sC[0][0] + idx * 4);
  }
#pragma unroll
  for (int rep = 0; rep < 2; ++rep) {
    const int idx = rep * 256 + tid;
    const int i = idx >> 4, j4 = (idx & 15) << 2;
    gload16(&zx[(size_t)(l0 + i) * DP + OFF_B + gb * 64 + j4], &sB[0][0] + idx * 4);
    gload16(&xcv[(size_t)(l0 + i) * DXB + gb * 64 + j4], &sx[0][0] + idx * 4);
  }

  float An[16], h[16];
  {
    const float* ap = A_log + (size_t)gb * 4096 + tid * 16;
#pragma unroll
    for (int n = 0; n < 16; ++n) An[n] = -__expf(ap[n]);
    const float* hp = Hcarry + (size_t)s * 32768 + (size_t)gb * 4096 + tid * 16;
#pragma unroll
    for (int nq = 0; nq < 4; ++nq) {
      const float4 h4 = *(const float4*)(hp + nq * 4);
      h[nq * 4] = h4.x; h[nq * 4 + 1] = h4.y; h[nq * 4 + 2] = h4.z; h[nq * 4 + 3] = h4.w;
    }
  }
  const float Dd = Dv[gb * 256 + tid];
  __syncthreads();

  const float* dtp = delta + (size_t)l0 * DI + gb * 256 + tid;
  const float* zp  = zx + (size_t)l0 * DP + OFF_Z + gb * 256 + tid;
  unsigned short* yp = ybuf + (size_t)l0 * DI + gb * 256 + tid;
  const int xj = ((lg >> 2) << 4) + p;
  const int bj = (lg >> 2) << 4;
  const int cj = lg << 4;

  float dtc = dtp[0], zc = zp[0];
  for (int i = 0; i < SEGLEN; ++i) {
    const float dt = dtc, zv = zc;
    if (i + 1 < SEGLEN) {
      dtc = dtp[(size_t)(i + 1) * DI];
      zc  = zp[(size_t)(i + 1) * DP];
    }
    const float xv = sx[i][xj];
    const float dtx = dt * xv;
    float y = 0.f;
#pragma unroll
    for (int nq = 0; nq < 4; ++nq) {
      const float4 b4 = *(const float4*)&sB[i][bj + nq * 4];
      const float4 c4 = *(const float4*)&sC[i][cj + nq * 4];
      const float bb[4] = {b4.x, b4.y, b4.z, b4.w};
      const float cc[4] = {c4.x, c4.y, c4.z, c4.w};
#pragma unroll
      for (int k = 0; k < 4; ++k) {
        const int n = nq * 4 + k;
        const float a = __expf(dt * An[n]);
        h[n] = fmaf(a, h[n], dtx * bb[k]);
        y = fmaf(h[n], cc[k], y);
      }
    }
    yp[(size_t)i * DI] = f2bf((y + Dd * xv) * siluf(zv));
  }
}

__global__ __launch_bounds__(256) void zero_f32(float* __restrict__ p, int n4)
{
  const int t = blockIdx.x * 256 + threadIdx.x;
  if (t < n4) ((float4*)p)[t] = make_float4(0.f, 0.f, 0.f, 0.f);
}

// ---------------------------------------------------------------------------
extern "C" void kernel_launch(void* const* d_in, const int* in_sizes, int n_in,
                              void* d_out, int out_size, void* d_ws, size_t ws_size,
                              hipStream_t stream)
{
  const float* hidden  = (const float*)d_in[0];
  const float* W_in    = (const float*)d_in[1];
  const float* conv_w  = (const float*)d_in[2];
  const float* conv_b  = (const float*)d_in[3];
  const float* W_dt    = (const float*)d_in[4];
  const float* dt_bias = (const float*)d_in[5];
  const float* A_log   = (const float*)d_in[6];
  const float* Dvec    = (const float*)d_in[7];
  const float* W_out   = (const float*)d_in[8];
  float* out = (float*)d_out;

  // --- workspace layout (lifetime-aliased; max footprint 80,740,352 B) ---
  float* ws = (float*)d_ws;
  float* zx     = ws;                       // [0, 10,616,832) f32 — alive all
  float* delta  = ws + 10616832;            // [10,616,832, 14,811,136) f32
  float* xcv    = ws + 14811136;            // [14,811,136, 15,859,712) f32
  float* Sbuf   = ws + 15859712;            // 131,072 f32
  float* Hbuf   = ws + 15990784;            // 2,097,152 f32 (ends 18,087,936)
  float* Hcarry = ws + 18087936;            // 2,097,152 f32 (ends 20,185,088)
  // phase-A aliases (dead before delta/xcv written):
  unsigned short* Abf  = (unsigned short*)(ws + 10616832);  // 2,097,152 u16
  unsigned short* WinT = (unsigned short*)(ws + 11665408);  // 5,308,416 u16
  // phase-D/E aliases:
  unsigned short* Ybf   = (unsigned short*)(ws + 15859712); // 4,194,304 u16 over S+H
  unsigned short* WoutT = (unsigned short*)(ws + 10616832); // 2,097,152 u16 over delta

  // 1. cast hidden -> bf16; transpose+cast W_in
  cast_bf16_k<<<dim3((L_SEQ * DM / 4) / 256), 256, 0, stream>>>(hidden, Abf, L_SEQ * DM / 4);
  transpose_cast_k<<<dim3(DP / 32, DM / 32), 256, 0, stream>>>(W_in, WinT, DM, DP);

  // 2. in-projection (bf16 MFMA, dbuf): zx = hidden @ W_in  (2048 x 5184, K=1024)
  mfma_gemm<0><<<dim3(41, 16), 256, 0, stream>>>(Abf, WinT, zx, DP, DP, DM, DM / 32);

  // 3. causal depthwise conv + silu
  conv_silu_k<<<dim3((L_SEQ * DXB) / 256), 256, 0, stream>>>(zx, conv_w, conv_b, xcv);

  // 4. delta = softplus(dtr @ W_dt + 2*dt_bias)  (fp32, K=64)
  gemm128<1><<<dim3(16, 16), 256, 0, stream>>>(
      zx, DP, OFF_DT, W_dt, DI, delta, DI, dt_bias, L_SEQ, DI, 0, DTR);

  // 5. scan pass 1: per-segment (S, H)
  scan_p1<<<dim3(8, NSEG), 256, 0, stream>>>(zx, delta, xcv, A_log, Sbuf, Hbuf);

  // 6. exclusive segment-carry scan
  scan_carry<<<dim3(128), 256, 0, stream>>>(A_log, Sbuf, Hbuf, Hcarry);

  // 7. scan pass 2 -> y (bf16) with fused D*x + silu(z) gate
  scan_p2<<<dim3(8, NSEG), 256, 0, stream>>>(zx, delta, xcv, A_log, Dvec, Hcarry, Ybf);

  // 8. transpose+cast W_out (into delta region, dead after scan_p2)
  transpose_cast_k<<<dim3(DM / 32, DI / 32), 256, 0, stream>>>(W_out, WoutT, DI, DM);

  // 9. out-projection (bf16 MFMA dbuf, split-K=4 atomic — small 8.4 MB output)
  zero_f32<<<dim3(out_size / 4 / 256), 256, 0, stream>>>(out, out_size / 4);
  mfma_gemm<1><<<dim3(8, 16, 4), 256, 0, stream>>>(Ybf, WoutT, out, DM, DM, DI, DI / 4 / 32);
}